// Round 5
// baseline (120.894 us; speedup 1.0000x reference)
//
#include <hip/hip_runtime.h>

#define HH 96
#define WW 96
#define OH 90
#define OW 90
#define NPATCH 8100
#define DD 147
#define NPROJ 256
#define TN 64         // patches per block in kernel A (M-tile)
#define KPAD 160      // K padded to 5*32 for MFMA
#define NKS 5         // K-steps of 32
#define NBUCK 4096
#define PGRP 16       // reduce: projections per block
#define NCH 64        // reduce: row chunks (grid.x)
#define KPB2 128      // reduce: rows per chunk
#define QSCALE 21.25f // u8 quant: 255/12, range +-6 sigma, zero at 128

typedef short bf16x8 __attribute__((ext_vector_type(8)));
typedef float f32x4 __attribute__((ext_vector_type(4)));

__device__ __forceinline__ unsigned short bf16_rne(float f) {
    unsigned u = __builtin_bit_cast(unsigned, f);
    u += 0x7FFFu + ((u >> 16) & 1u);
    return (unsigned short)(u >> 16);
}
__device__ __forceinline__ float bf16_f(unsigned short h) {
    return __builtin_bit_cast(float, (unsigned)h << 16);
}

// v_sad_u8: byte-wise |a-b| sum of 4 lanes + 32-bit accumulate, 1 VALU op.
__device__ __forceinline__ unsigned sad4(unsigned x, unsigned y, unsigned a) {
    unsigned d;
    asm("v_sad_u8 %0, %1, %2, %3" : "=v"(d) : "v"(x), "v"(y), "v"(a));
    return d;
}

// ---------------------------------------------------------------------------
// Kernel A (v8): as R4 (proven) + LDS offset table for the unfold gather:
// offt[d] = c*HH*WW + di*WW + dj precomputed once/block; staging thread
// (t = tid>>3, u0 = tid&7) handles patch n0+t, units u0+8*it — n/OW once per
// thread, per-element address = base + offt[d]. Stored values bit-identical.
// Projection GEMM = split-bf16 MFMA (hi*hi + hi*lo + lo*hi), f32 accumulate.
// D layout (m89-verified): col = lane&15, row = (lane>>4)*4 + reg.
// ---------------------------------------------------------------------------
__global__ __launch_bounds__(512, 2)
void patch_proj_kernel(const float* __restrict__ x, const float* __restrict__ y,
                       const float* __restrict__ rnd,
                       int* __restrict__ xm8, int* __restrict__ ym8,
                       int* __restrict__ xt8, int* __restrict__ yt8,
                       float* __restrict__ pxT, float* __restrict__ pyT,
                       float* __restrict__ out)
{
    __shared__ unsigned short sh[2][TN * KPAD];   // hi, lo planes: 40960 B
    __shared__ int offt[KPAD];                    // unfold offsets: 640 B
    const int tid = threadIdx.x;
    const int n0 = blockIdx.x * TN;
    const int img = blockIdx.y;
    const float* __restrict__ src = img ? y : x;
    int* __restrict__ m8 = img ? ym8 : xm8;
    int* __restrict__ t8 = img ? yt8 : xt8;
    float* __restrict__ pT = img ? pyT : pxT;
    if (blockIdx.x == 0 && img == 0 && tid == 0) out[0] = 0.0f;

    const int wv = tid >> 6, lane = tid & 63;
    const int cl = lane & 15, qk = lane >> 4;

    // ---- offset table: offt[d] = src offset of dim d at (oy,ox)=(0,0) ----
    if (tid < KPAD) {
        int o = -1;
        if (tid < DD) {
            const int c = tid / 49, r = tid - c * 49;
            const int di = r / 7, dj = r - di * 7;
            o = c * (HH * WW) + di * WW + dj;
        }
        offt[tid] = o;
    }

    // ---- B-operand fragments in registers (wave wv -> proj cols 32wv..+31).
    bf16x8 bh[NKS][2], bl[NKS][2];
#pragma unroll
    for (int ks = 0; ks < NKS; ++ks) {
#pragma unroll
        for (int nt = 0; nt < 2; ++nt) {
            const int col = wv * 32 + nt * 16 + cl;
#pragma unroll
            for (int j = 0; j < 8; ++j) {
                const int k = ks * 32 + qk * 8 + j;
                const float v = (k < DD) ? rnd[k * NPROJ + col] : 0.f;
                const unsigned short h = bf16_rne(v);
                bh[ks][nt][j] = (short)h;
                bl[ks][nt][j] = (short)bf16_rne(v - bf16_f(h));
            }
        }
    }
    __syncthreads();   // offt ready

    // ---- fused staging: thread (t = tid>>3, u0 = tid&7), 5 units each.
    // LDS frag pos: mt=t>>4, r=t&15, ks=d>>5, q=(d&31)>>3, j=d&7
    //   -> (((mt*NKS+ks)*4+q)*16+r)*8 + j ; d0%4==0 keeps 4 elems contiguous.
    {
        const int t = tid >> 3;
        const int u0 = tid & 7;
        const int n = n0 + t;
        const bool nok = n < NPATCH;
        int baseoff = 0;
        if (nok) {
            const int oy = n / OW, ox = n - oy * OW;
            baseoff = oy * WW + ox;
        }
        const int mt = t >> 4, r16 = t & 15;
#pragma unroll
        for (int it = 0; it < 5; ++it) {
            const int u = u0 + 8 * it;
            const int d0 = 4 * u;
            unsigned short h4[4], l4[4];
#pragma unroll
            for (int e = 0; e < 4; ++e) {
                const int o = offt[d0 + e];
                const float v = (nok && o >= 0) ? src[baseoff + o] : 0.f;
                const unsigned short hi = bf16_rne(v);
                h4[e] = hi;
                l4[e] = bf16_rne(v - bf16_f(hi));
            }
            const int ks = d0 >> 5, q = (d0 & 31) >> 3, jb = d0 & 7;  // jb in {0,4}
            const int fidx = (((mt * NKS + ks) * 4 + q) * 16 + r16) * 8 + jb;
            ushort4 hv; hv.x = h4[0]; hv.y = h4[1]; hv.z = h4[2]; hv.w = h4[3];
            ushort4 lv; lv.x = l4[0]; lv.y = l4[1]; lv.z = l4[2]; lv.w = l4[3];
            *(ushort4*)&sh[0][fidx] = hv;
            *(ushort4*)&sh[1][fidx] = lv;
            if (nok) {
                unsigned w = 0;
#pragma unroll
                for (int e = 0; e < 4; ++e) {
                    float f = fmaf(bf16_f(h4[e]), QSCALE, 128.5f);
                    f = fminf(fmaxf(f, 0.f), 255.f);
                    w |= ((unsigned)f) << (8 * e);
                }
                if (u < 32) m8[(size_t)n * 32 + u] = (int)w;
                else        t8[(size_t)n * 8 + (u - 32)] = (int)w;
            }
        }
    }
    __syncthreads();

    // ---- projection GEMM ----
    f32x4 acc[4][2];
#pragma unroll
    for (int mt = 0; mt < 4; ++mt)
#pragma unroll
        for (int nt = 0; nt < 2; ++nt)
            acc[mt][nt] = (f32x4){0.f, 0.f, 0.f, 0.f};

#pragma unroll
    for (int ks = 0; ks < NKS; ++ks) {
#pragma unroll
        for (int mt = 0; mt < 4; ++mt) {
            const int base = ((mt * NKS + ks) * 64 + lane) * 8;
            const bf16x8 ah = *(const bf16x8*)&sh[0][base];
            const bf16x8 al = *(const bf16x8*)&sh[1][base];
#pragma unroll
            for (int nt = 0; nt < 2; ++nt) {
                acc[mt][nt] = __builtin_amdgcn_mfma_f32_16x16x32_bf16(ah, bh[ks][nt], acc[mt][nt], 0, 0, 0);
                acc[mt][nt] = __builtin_amdgcn_mfma_f32_16x16x32_bf16(ah, bl[ks][nt], acc[mt][nt], 0, 0, 0);
                acc[mt][nt] = __builtin_amdgcn_mfma_f32_16x16x32_bf16(al, bh[ks][nt], acc[mt][nt], 0, 0, 0);
            }
        }
    }

    // ---- write pT: D col = lane&15 (proj), row = qk*4 + reg (patch) ----
#pragma unroll
    for (int mt = 0; mt < 4; ++mt) {
        const int patch = n0 + mt * 16 + qk * 4;
#pragma unroll
        for (int nt = 0; nt < 2; ++nt) {
            const int proj = wv * 32 + nt * 16 + cl;
            float* rowp = pT + (size_t)proj * NPATCH + patch;
            if (patch + 3 < NPATCH) {
                *(f32x4*)rowp = acc[mt][nt];
            } else {
#pragma unroll
                for (int e = 0; e < 4; ++e)
                    if (patch + e < NPATCH) rowp[e] = acc[mt][nt][e];
            }
        }
    }
}

// ---------------------------------------------------------------------------
// Kernel B (v12): CONCURRENT paired bucket-rank. One block per projection,
// 1024 threads: waves 0-7 rank the x-column while waves 8-15 rank the
// y-column (independent hist/cnt/skey per half; 147 KB LDS, 1 block/CU =
// same 16 waves/CU as v11 but the two passes' barriers and latency chains
// now overlap instead of serializing). Rank math identical (affine buckets,
// hist->scan->scatter->count-smaller; tie poison 0xFFFF clamped).
// x-half keeps ranks in registers; y-half builds iy in LDS; x-half emits
// fused partner[p][i] = iy[xr[i]] with coalesced u16 stores.
// ---------------------------------------------------------------------------
__global__ __launch_bounds__(1024, 4)
void rank_kernel(const float* __restrict__ pT,
                 unsigned short* __restrict__ partner)
{
    __shared__ unsigned hist[2][NBUCK];        // 32 KB
    __shared__ unsigned cnt[2][NBUCK];         // 32 KB
    __shared__ float    skey[2][8192];         // 64 KB
    __shared__ unsigned short iyl[8192];       // 16 KB
    __shared__ unsigned wsum[2][8];
    const int p = blockIdx.x;
    const int tid = threadIdx.x;
    const int half = tid >> 9;                 // 0 = x column, 1 = y column
    const int t5 = tid & 511;
    const int lane = tid & 63;
    const int wid5 = t5 >> 6;                  // wave within half (0..7)

    const float* __restrict__ col = pT + (size_t)(p + half * NPROJ) * NPATCH;
    unsigned* H  = hist[half];
    unsigned* Cn = cnt[half];
    float*    SK = skey[half];

    {
        const uint4 z = make_uint4(0, 0, 0, 0);
        ((uint4*)H)[t5]        = z;
        ((uint4*)H)[t5 + 512]  = z;
        ((uint4*)Cn)[t5]       = z;
        ((uint4*)Cn)[t5 + 512] = z;
        if (half) {   // iy poison: tie-collapsed ranks stay 0xFFFF
            const uint4 f = make_uint4(~0u, ~0u, ~0u, ~0u);
            ((uint4*)iyl)[t5]       = f;
            ((uint4*)iyl)[t5 + 512] = f;
        }
    }
    __syncthreads();

    float k[16];
    int bk[16];
#pragma unroll
    for (int t = 0; t < 16; ++t) {
        const int i = t5 + 512 * t;
        if (i < NPATCH) {
            const float v = col[i];
            k[t] = v;
            int b = (int)((v + 51.2f) * 40.0f);
            b = b < 0 ? 0 : (b > NBUCK - 1 ? NBUCK - 1 : b);
            bk[t] = b;
            atomicAdd(&H[b], 1u);
        } else {
            k[t] = 0.f;
            bk[t] = -1;
        }
    }
    __syncthreads();

    {   // exclusive scan of 4096 buckets per half (8 buckets/thread)
        const int b0 = t5 * 8;
        unsigned h[8];
#pragma unroll
        for (int q = 0; q < 8; ++q) h[q] = H[b0 + q];
        unsigned tsum = 0;
#pragma unroll
        for (int q = 0; q < 8; ++q) tsum += h[q];
        unsigned acc = tsum;
#pragma unroll
        for (int d = 1; d < 64; d <<= 1) {
            const unsigned v = __shfl_up(acc, d, 64);
            if (lane >= d) acc += v;
        }
        const unsigned wexcl = acc - tsum;
        if (lane == 63) wsum[half][wid5] = acc;
        __syncthreads();
        if (t5 == 0) {
            unsigned roff = 0;
#pragma unroll
            for (int w = 0; w < 8; ++w) {
                const unsigned tt = wsum[half][w];
                wsum[half][w] = roff;
                roff += tt;
            }
        }
        __syncthreads();
        unsigned run = wsum[half][wid5] + wexcl;
#pragma unroll
        for (int q = 0; q < 8; ++q) { Cn[b0 + q] = run; run += h[q]; }
    }
    __syncthreads();

#pragma unroll
    for (int t = 0; t < 16; ++t) {
        if (bk[t] >= 0) {
            const unsigned pos = atomicAdd(&Cn[bk[t]], 1u);
            SK[pos] = k[t];
        }
    }
    __syncthreads();

    unsigned short xr[16];
#pragma unroll
    for (int t = 0; t < 16; ++t) {
        if (bk[t] < 0) continue;
        const int b = bk[t];
        const unsigned end = Cn[b];
        const unsigned cb = H[b];
        const unsigned start = end - cb;
        const float myk = k[t];
        unsigned r = start;
        for (unsigned s2 = start; s2 < end; ++s2)
            r += (SK[s2] < myk) ? 1u : 0u;
        if (half == 0) xr[t] = (unsigned short)r;                 // x-rank
        else           iyl[r] = (unsigned short)(t5 + 512 * t);   // iy[rank]=i
    }
    __syncthreads();

    // ---- emit fused partner (x-half only): partner[p][i] = clamp(iy[xr[i]])
    if (half == 0) {
#pragma unroll
        for (int t = 0; t < 16; ++t) {
            const int i = t5 + 512 * t;
            if (i >= NPATCH) continue;
            const unsigned short j = iyl[xr[t]];
            partner[(size_t)p * NPATCH + i] =
                (j < NPATCH) ? j : (unsigned short)(NPATCH - 1);
        }
    }
}

// ---------------------------------------------------------------------------
// Kernel C (v11, unchanged — at its L2 gather floor): SAD reduce; staging
// reads the fused partner array with one coalesced load per element.
// L1 via v_sad_u8 on linear-u8 rows: 1 VALU op per 4 element-pairs.
// ---------------------------------------------------------------------------
__global__ __launch_bounds__(256, 4)
void reduce_kernel(const uint4* __restrict__ xm8, const uint4* __restrict__ ym8,
                   const uint4* __restrict__ xt8, const uint4* __restrict__ yt8,
                   const unsigned short* __restrict__ partner,
                   float* __restrict__ out)
{
    __shared__ unsigned short sp[PGRP * KPB2];
    const int p0 = blockIdx.y * PGRP;
    const int i0 = blockIdx.x * KPB2;
    const int iend = min(i0 + KPB2, NPATCH);
    const int tid = threadIdx.x;
    const int wave = tid >> 6, lane = tid & 63;

    for (int idx = tid; idx < PGRP * KPB2; idx += 256) {
        const int pp = idx >> 7, r = idx & 127;
        int src = i0 + r;
        src = src < NPATCH ? src : NPATCH - 1;
        sp[idx] = partner[(size_t)(p0 + pp) * NPATCH + src];
    }
    __syncthreads();

    unsigned uacc = 0;   // max: 1280 elems * 255 = 326K << 2^32

    // ---- main pass: d = 0..127 ----
    {
        const int g = lane >> 3;
        const int u = lane & 7;
#pragma unroll
        for (int it = 0; it < 4; ++it) {
            const int i = i0 + wave * 8 + it * 32;
            const uint4 xa = xm8[(size_t)i * 8 + lane];   // OOB -> ym8, masked
            int jj[PGRP];
#pragma unroll
            for (int pp = 0; pp < PGRP; ++pp)
                jj[pp] = sp[pp * KPB2 + (i - i0) + g];
            uint4 ya[PGRP];
#pragma unroll
            for (int pp = 0; pp < PGRP; ++pp)
                ya[pp] = ym8[(size_t)jj[pp] * 8 + u];
            unsigned s0 = 0, s1 = 0;
#pragma unroll
            for (int pp = 0; pp < PGRP; ++pp) {
                s0 = sad4(xa.x, ya[pp].x, s0);
                s1 = sad4(xa.y, ya[pp].y, s1);
                s0 = sad4(xa.z, ya[pp].z, s0);
                s1 = sad4(xa.w, ya[pp].w, s1);
            }
            uacc += (i + g < iend) ? (s0 + s1) : 0u;
        }
    }

    // ---- tail pass: d = 128..159 (pad bytes quant(0)=128 both sides -> 0) ----
    {
        const int g2 = lane >> 1;
        const int u2 = lane & 1;
        const int i2 = i0 + wave * 32;
        const uint4 xa = xt8[(size_t)i2 * 2 + lane];      // OOB -> yt8, masked
        int jj[PGRP];
#pragma unroll
        for (int pp = 0; pp < PGRP; ++pp)
            jj[pp] = sp[pp * KPB2 + (i2 - i0) + g2];
        uint4 ya[PGRP];
#pragma unroll
        for (int pp = 0; pp < PGRP; ++pp)
            ya[pp] = yt8[(size_t)jj[pp] * 2 + u2];
        unsigned s0 = 0, s1 = 0;
#pragma unroll
        for (int pp = 0; pp < PGRP; ++pp) {
            s0 = sad4(xa.x, ya[pp].x, s0);
            s1 = sad4(xa.y, ya[pp].y, s1);
            s0 = sad4(xa.z, ya[pp].z, s0);
            s1 = sad4(xa.w, ya[pp].w, s1);
        }
        uacc += (i2 + g2 < iend) ? (s0 + s1) : 0u;
    }

    float facc = (float)uacc;
#pragma unroll
    for (int o = 32; o > 0; o >>= 1) facc += __shfl_down(facc, o, 64);

    __shared__ float sred[4];
    if (lane == 0) sred[wave] = facc;
    __syncthreads();
    if (tid == 0) {
        const float s = sred[0] + sred[1] + sred[2] + sred[3];
        const float scale = (float)(1.0 / ((double)NPROJ * (double)NPATCH *
                                           (double)DD * (double)QSCALE));
        atomicAdd(out, s * scale);
    }
}

// ---------------------------------------------------------------------------
extern "C" void kernel_launch(void* const* d_in, const int* in_sizes, int n_in,
                              void* d_out, int out_size, void* d_ws, size_t ws_size,
                              hipStream_t stream)
{
    const float* x   = (const float*)d_in[0];
    const float* y   = (const float*)d_in[1];
    const float* rnd = (const float*)d_in[2];

    char* ws = (char*)d_ws;
    // workspace layout (16B-aligned; xm8|ym8 and xt8|yt8 adjacent so masked
    // OOB reads in kernel C stay in-bounds; pxT|pyT adjacent for rank kernel):
    int* xm8 = (int*)(ws + 0);          // 8100*128 = 1,036,800
    int* ym8 = (int*)(ws + 1036800);    // 1,036,800
    int* xt8 = (int*)(ws + 2073600);    // 8100*32  =   259,200
    int* yt8 = (int*)(ws + 2332800);    //               259,200
    float* pxT = (float*)(ws + 2592000);     // 256*8100*4 = 8,294,400
    float* pyT = (float*)(ws + 10886400);    //             8,294,400
    unsigned short* partner = (unsigned short*)(ws + 19180800);  // 4,147,200
    // high-water: 23,328,000 bytes
    float* out = (float*)d_out;

    hipLaunchKernelGGL(patch_proj_kernel, dim3((NPATCH + TN - 1) / TN, 2), dim3(512), 0, stream,
                       x, y, rnd, xm8, ym8, xt8, yt8, pxT, pyT, out);
    hipLaunchKernelGGL(rank_kernel, dim3(NPROJ), dim3(1024), 0, stream,
                       pxT, partner);
    hipLaunchKernelGGL(reduce_kernel, dim3(NCH, NPROJ / PGRP), dim3(256), 0, stream,
                       (const uint4*)xm8, (const uint4*)ym8,
                       (const uint4*)xt8, (const uint4*)yt8, partner, out);
}